// Round 7
// baseline (38.438 us; speedup 1.0000x reference)
//
#include <hip/hip_runtime.h>
#include <math.h>
#include <stdint.h>

#define BB 4
#define CC 129
#define HH 512
#define WW 512
#define HWSZ (HH*WW)
#define JJ 512
#define KK 1024
#define NKP (JJ+KK)
#define RAD 7
#define TS 32
#define HL (TS + 2*RAD)      // 46
#define TPB 256              // tiles per batch (16x16 of 32x32)
#define SLOTS 32             // max peaks per tile (geometry bound 16; ties margin)
#define NL 2048              // max ranked candidates (expected n ~= 1165)
#define NMS_THRESH 0.99f
#define JDB 256              // junction-desc blocks (8 kps each)
#define SENT 0xFF800000FFFFFFFFULL

// ws layout (bytes)
static const size_t OFF_TCNT  = 0;                       // BB*TPB ints = 4 KB
static const size_t OFF_TKEYS = 4096;                    // BB*TPB*SLOTS*8 = 256 KB

// K1: blocks [0,JDB) do junction descriptors (pure scattered gather, latency
// hides under the NMS blocks' LDS-bound compute); blocks [JDB, JDB+1024) do
// tiled 15x15 NMS (separable, in LDS) writing per-tile counts+slots (no global
// atomics; counts overwritten every replay -> no memset dispatch needed).
__global__ __launch_bounds__(256)
void k_nms(const float* __restrict__ in, const int* __restrict__ juncs,
           int* __restrict__ tileCnt, uint64_t* __restrict__ tileKeys,
           float* __restrict__ out_kp, float* __restrict__ out_desc,
           float* __restrict__ out_sc) {
    __shared__ float s[HL*HL];      // 2116 floats
    __shared__ float hm[HL*TS];     // 1472 floats
    __shared__ int tcnt;
    const int tid = threadIdx.x, blk = blockIdx.x;

    if (blk < JDB) {
        // ---- junction descriptors: 8 kps/block, one 32-lane group per kp ----
        int g2 = tid >> 5, l = tid & 31;
        int j  = blk*8 + g2;              // 0..2047
        int jb = j >> 9, jk = j & 511;
        int kx = juncs[(jb*JJ + jk)*2 + 0];
        int ky = juncs[(jb*JJ + jk)*2 + 1];
        int fi = ky*WW + kx;
        const float* fp = in + (size_t)jb*CC*HWSZ + HWSZ + fi;
        float a0 = fp[(size_t)(l      )*HWSZ];
        float a1 = fp[(size_t)(l + 32 )*HWSZ];
        float a2 = fp[(size_t)(l + 64 )*HWSZ];
        float a3 = fp[(size_t)(l + 96 )*HWSZ];
        float sq = a0*a0 + a1*a1 + a2*a2 + a3*a3;
        for (int m = 1; m < 32; m <<= 1) sq += __shfl_xor(sq, m, 32);
        float nrm = fmaxf(sqrtf(sq), 1e-12f);
        int go = jb*NKP + jk;
        float* dp = out_desc + (size_t)go * 128;
        dp[l]      = a0 / nrm;
        dp[l + 32] = a1 / nrm;
        dp[l + 64] = a2 / nrm;
        dp[l + 96] = a3 / nrm;
        if (l == 0) {
            out_kp[2*go]     = (float)kx;
            out_kp[2*go + 1] = (float)ky;
            out_sc[go]       = 1.0f;
        }
        return;
    }

    // ---- tiled NMS ----
    int blk2 = blk - JDB;
    int b = blk2 >> 8, t = blk2 & 255;
    int ty = t >> 4, tx = t & 15;
    int by = ty*TS - RAD, bx = tx*TS - RAD;
    const float* heat = in + (size_t)b * CC * HWSZ;
    if (tid == 0) tcnt = 0;
    for (int i = tid; i < HL*HL; i += 256) {
        int r = i / HL, c = i - r*HL;
        int gy = by + r, gx = bx + c;
        s[i] = (gy >= 0 && gy < HH && gx >= 0 && gx < WW)
                 ? heat[gy*WW + gx] : -INFINITY;
    }
    __syncthreads();
    for (int i = tid; i < HL*TS; i += 256) {      // horizontal 15-max
        int r = i >> 5, c = i & 31;
        const float* sp = s + r*HL + c;
        float m = sp[0];
        #pragma unroll
        for (int k = 1; k < 15; ++k) m = fmaxf(m, sp[k]);
        hm[i] = m;
    }
    __syncthreads();
    uint64_t* tk = tileKeys + (size_t)blk2 * SLOTS;
    for (int i = tid; i < TS*TS; i += 256) {      // vertical 15-max + collect
        int r = i >> 5, c = i & 31;
        float v = s[(r+RAD)*HL + (c+RAD)];
        if (v > NMS_THRESH) {
            const float* hp = hm + r*TS + c;
            float m = hp[0];
            #pragma unroll
            for (int k = 1; k < 15; ++k) m = fmaxf(m, hp[k*TS]);
            if (v == m) {                          // exact fp equality, as ref
                int pos = atomicAdd(&tcnt, 1);     // LDS atomic, block-local
                if (pos < SLOTS) {
                    uint32_t idx = (uint32_t)((ty*TS + r)*WW + (tx*TS + c));
                    tk[pos] = ((uint64_t)__float_as_uint(v) << 32)
                            | (uint32_t)(~idx);
                }
            }
        }
    }
    __syncthreads();
    if (tid == 0) tileCnt[blk2] = (tcnt < SLOTS) ? tcnt : SLOTS;
}

// K2: compact batch candidates to LDS (deterministic tile-major order via
// scan), PREFETCH the block's 16 kps' descriptor loads, then rank-count
// (rank = #{j : key_j > key_i}; exact top_k semantics, order-invariant =>
// deterministic) and v0 while loads are in flight, then normalize + write
// directly to output slot `rank`.
__global__ __launch_bounds__(256)
void k_rankdesc(const float* __restrict__ in,
                const int* __restrict__ tileCnt, const uint64_t* __restrict__ tileKeys,
                float* __restrict__ out_kp, float* __restrict__ out_desc,
                float* __restrict__ out_sc) {
    __shared__ uint64_t sk[NL];          // 16 KB
    __shared__ int sca[TPB], scb[TPB];
    __shared__ int part[256];
    __shared__ float wmax[4];
    const int tid = threadIdx.x, blk = blockIdx.x;
    int b = blk >> 7, chunk = blk & 127;
    int i0 = chunk * 16;

    // ---- compact ----
    int cnt_t = tileCnt[b*TPB + tid];    // tid in [0,256) == TPB
    sca[tid] = cnt_t;
    __syncthreads();
    int* src = sca; int* dst = scb;
    for (int off = 1; off < TPB; off <<= 1) {
        dst[tid] = src[tid] + ((tid >= off) ? src[tid - off] : 0);
        __syncthreads();
        int* tmp = src; src = dst; dst = tmp;
    }
    int off_t = src[tid] - cnt_t;        // exclusive, tile-major (deterministic)
    int n = src[TPB-1]; if (n > NL) n = NL;
    const uint64_t* tkb = tileKeys + (size_t)(b*TPB) * SLOTS;
    for (int j = 0; j < cnt_t; ++j) {
        int o = off_t + j;
        if (o < NL) sk[o] = tkb[(size_t)tid*SLOTS + j];
    }
    __syncthreads();

    // ---- prefetch: issue gather loads for this thread's two kps ----
    const int hw = tid >> 5, l = tid & 31;
    const int sA = hw, sB = hw + 8;
    uint64_t keyA = (i0 + sA < n) ? sk[i0 + sA] : SENT;
    uint64_t keyB = (i0 + sB < n) ? sk[i0 + sB] : SENT;
    int idxA = (int)(~(uint32_t)keyA) & (HWSZ-1);
    int idxB = (int)(~(uint32_t)keyB) & (HWSZ-1);
    const float* fbase = in + (size_t)b*CC*HWSZ + HWSZ;
    const float* fpA = fbase + idxA;
    const float* fpB = fbase + idxB;
    float a0 = fpA[(size_t)(l      )*HWSZ];
    float a1 = fpA[(size_t)(l + 32 )*HWSZ];
    float a2 = fpA[(size_t)(l + 64 )*HWSZ];
    float a3 = fpA[(size_t)(l + 96 )*HWSZ];
    float b0 = fpB[(size_t)(l      )*HWSZ];
    float b1 = fpB[(size_t)(l + 32 )*HWSZ];
    float b2 = fpB[(size_t)(l + 64 )*HWSZ];
    float b3 = fpB[(size_t)(l + 96 )*HWSZ];

    // ---- v0 (wave partial) + rank partials, one shared barrier ----
    float mx = -INFINITY;
    for (int i = tid; i < n; i += 256)
        mx = fmaxf(mx, __uint_as_float((uint32_t)(sk[i] >> 32)));
    for (int m = 1; m < 64; m <<= 1) mx = fmaxf(mx, __shfl_xor(mx, m, 64));
    if ((tid & 63) == 0) wmax[tid >> 6] = mx;

    {
        int it = tid & 15, sub = tid >> 4;
        uint64_t key = (i0 + it < n) ? sk[i0 + it] : SENT;
        int jc = (n + 15) >> 4;
        int j0 = sub*jc, j1 = j0 + jc; if (j1 > n) j1 = n;
        int r = 0;
        for (int j = j0; j < j1; ++j) r += (sk[j] > key);
        part[tid] = r;
    }
    __syncthreads();
    float v0 = fmaxf(fmaxf(wmax[0], wmax[1]), fmaxf(wmax[2], wmax[3]));

    // ---- finalize both kps: rank sum, normalize, write to slot `rank` ----
    #pragma unroll
    for (int pick = 0; pick < 2; ++pick) {
        int s2 = pick ? sB : sA;
        uint64_t key = pick ? keyB : keyA;
        float c0 = pick ? b0 : a0, c1 = pick ? b1 : a1;
        float c2 = pick ? b2 : a2, c3 = pick ? b3 : a3;
        int i_ = i0 + s2;
        int rank;
        if (i_ < n) {
            rank = 0;
            #pragma unroll
            for (int q = 0; q < 16; ++q) rank += part[q*16 + s2];
        } else rank = i_;                 // sentinel: identity (only if n < KK)
        if (rank < KK) {
            float v = __uint_as_float((uint32_t)(key >> 32));
            int rr = (int)(~(uint32_t)key);
            int kx = rr & (WW-1), ky = (rr >> 9) & (HH-1);
            float sq = c0*c0 + c1*c1 + c2*c2 + c3*c3;
            for (int m = 1; m < 32; m <<= 1) sq += __shfl_xor(sq, m, 32);
            float nrm = fmaxf(sqrtf(sq), 1e-12f);
            int go = b*NKP + JJ + rank;
            float* dp = out_desc + (size_t)go * 128;
            dp[l]      = c0 / nrm;
            dp[l + 32] = c1 / nrm;
            dp[l + 64] = c2 / nrm;
            dp[l + 96] = c3 / nrm;
            if (l == 0) {
                out_kp[2*go]     = (float)kx;
                out_kp[2*go + 1] = (float)ky;
                out_sc[go]       = v / v0;
            }
        }
    }
}

extern "C" void kernel_launch(void* const* d_in, const int* in_sizes, int n_in,
                              void* d_out, int out_size, void* d_ws, size_t ws_size,
                              hipStream_t stream) {
    const float* in  = (const float*)d_in[0];
    const int* juncs = (const int*)d_in[1];
    float* out       = (float*)d_out;

    char* ws = (char*)d_ws;
    int*      tileCnt  = (int*)(ws + OFF_TCNT);
    uint64_t* tileKeys = (uint64_t*)(ws + OFF_TKEYS);

    float* out_kp   = out;                                          // BB*NKP*2
    float* out_desc = out + (size_t)BB*NKP*2;                       // BB*NKP*128
    float* out_sc   = out + (size_t)BB*NKP*2 + (size_t)BB*NKP*128;  // BB*NKP

    k_nms     <<<JDB + BB*TPB, 256, 0, stream>>>(in, juncs, tileCnt, tileKeys,
                                                 out_kp, out_desc, out_sc);
    k_rankdesc<<<512,          256, 0, stream>>>(in, tileCnt, tileKeys,
                                                 out_kp, out_desc, out_sc);
}